// Round 10
// baseline (57.080 us; speedup 1.0000x reference)
//
#include <hip/hip_runtime.h>
#include <hip/hip_bf16.h>

typedef __attribute__((ext_vector_type(8))) short short8;
typedef __attribute__((ext_vector_type(4))) float floatx4;

#define B_ROWS 8192
#define DIM    128
#define NSPLIT 16
#define JSPAN  (B_ROWS / NSPLIT)        // 512 cols per split
#define NTILE  (JSPAN / 16)             // 32 j-tiles of 16 cols
#define WAVES  4
#define RPW    64                       // rows per wave (4 x 16-row MFMA sets)
#define BM     (WAVES * RPW)            // 256 rows per block
#define NRB    (B_ROWS / BM)            // 32 row-blocks -> 512 blocks = 2/CU
#define BIAS   4096.0f
#define KOFF   64.0f                    // keeps atomic keys strictly positive

// Fragment-ordered buffer xf: for 16-row tile t, k-slice kk (0..3), lane l (0..63):
//   bf16 index = t*2048 + kk*512 + l*8 + e
// = element (row = t*16 + (l&15), k = kk*32 + (l>>4)*8 + e) — the exact
// mfma_f32_16x16x32_bf16 A/B fragment layout. One tile = 4KB contiguous.

// ws layout
#define OFF_SQ  (2u << 20)                 // after 2MB xf
#define OFF_KP  (OFF_SQ + (64u << 10))     // int keys, 32KB
#define OFF_KN  (OFF_KP + (32u << 10))     // int keys, 32KB
#define OFF_ACC (OFF_KN + (32u << 10))     // float sum, int done

// ---------------- prep: f32 -> bf16 fragment-order + norms + key/acc init ----------------
// R6's exact prep (2048 blocks) + kp/kn init.
__global__ __launch_bounds__(256) void prep_kernel(const float* __restrict__ x,
                                                   __hip_bfloat16* __restrict__ xf,
                                                   float* __restrict__ sq,
                                                   int* __restrict__ kp,
                                                   int* __restrict__ kn,
                                                   float* __restrict__ acc_sum,
                                                   int* __restrict__ done) {
    const int gid = blockIdx.x * 256 + threadIdx.x;
    if (gid < B_ROWS) { kp[gid] = 0; kn[gid] = 0x7F7F7F7F; }
    if (gid == 0) { acc_sum[0] = 0.f; done[0] = 0; }

    const int row  = blockIdx.x * 4 + (threadIdx.x >> 6);
    const int lane = threadIdx.x & 63;   // holds k = 2*lane, 2*lane+1
    const float2 v = *reinterpret_cast<const float2*>(x + row * DIM + lane * 2);
    __hip_bfloat162 b2;
    b2.x = __float2bfloat16(v.x);
    b2.y = __float2bfloat16(v.y);
    // fragment-order address for k0 = 2*lane
    const int kk = lane >> 4;
    const int g  = (lane >> 2) & 3;
    const int e  = (lane & 3) * 2;
    const int idx = (row >> 4) * 2048 + kk * 512 + (g * 16 + (row & 15)) * 8 + e;
    *reinterpret_cast<__hip_bfloat162*>(xf + idx) = b2;
    float s = v.x * v.x + v.y * v.y;
    #pragma unroll
    for (int m = 1; m < 64; m <<= 1) s += __shfl_xor(s, m, 64);
    if (lane == 0) sq[row] = s;
}

// ---------------- main: R6 structure, atomic-key outputs ----------------
// grid = (NRB, NSPLIT), block = 256 (4 independent waves), 2 waves/SIMD.
// Wave owns 64 rows; streams the split's 32 B-tiles via depth-2 named register
// prefetch, barrier-free. t = sq_j - 2*dot + BIAS*same; immediate max/min.
// Outputs: idempotent atomicMax/Min on int-punned positive float keys.
__global__ __launch_bounds__(256, 2) void main_kernel(
    const __hip_bfloat16* __restrict__ xf,
    const float* __restrict__ sq,
    const int*  __restrict__ lab,
    int* __restrict__ kp,
    int* __restrict__ kn) {
    const int tid  = threadIdx.x;
    const int lane = tid & 63;
    const int wave = tid >> 6;
    const int l15  = lane & 15;
    const int g    = lane >> 4;
    const int rowbase = blockIdx.x * BM + wave * RPW;
    const int split   = blockIdx.y;
    const int jstart  = split * JSPAN;

    // A fragments: 4 sets x 16 rows, contiguous loads from xf
    short8 a[4][4];
    #pragma unroll
    for (int s = 0; s < 4; ++s) {
        const __hip_bfloat16* ap = xf + ((size_t)(rowbase >> 4) + s) * 2048 + lane * 8;
        #pragma unroll
        for (int kk = 0; kk < 4; ++kk)
            a[s][kk] = *reinterpret_cast<const short8*>(ap + kk * 512);
    }
    int labi[4][4];
    #pragma unroll
    for (int s = 0; s < 4; ++s)
        #pragma unroll
        for (int q = 0; q < 4; ++q)
            labi[s][q] = lab[rowbase + s * 16 + g * 4 + q];

    float mx[4][4], mn[4][4];
    #pragma unroll
    for (int s = 0; s < 4; ++s)
        #pragma unroll
        for (int q = 0; q < 4; ++q) { mx[s][q] = -INFINITY; mn[s][q] = INFINITY; }

    const __hip_bfloat16* bbase = xf + (size_t)(jstart >> 4) * 2048 + lane * 8;

    short8 bA[4], bB[4];
    float sqA, sqB; int labA, labB;
    #pragma unroll
    for (int kk = 0; kk < 4; ++kk) {
        bA[kk] = *reinterpret_cast<const short8*>(bbase + kk * 512);
        bB[kk] = *reinterpret_cast<const short8*>(bbase + 2048 + kk * 512);
    }
    sqA  = sq[jstart + l15];          labA = lab[jstart + l15];
    sqB  = sq[jstart + 16 + l15];     labB = lab[jstart + 16 + l15];

    float tA[4][4], tB[4][4];

    #define MFMA_TILE(BB, T, SQJ, LABJ)                                         \
    do {                                                                        \
        floatx4 acc[4];                                                         \
        _Pragma("unroll")                                                       \
        for (int s = 0; s < 4; ++s) acc[s] = (floatx4){0.f, 0.f, 0.f, 0.f};     \
        _Pragma("unroll")                                                       \
        for (int kk = 0; kk < 4; ++kk) {                                        \
            _Pragma("unroll")                                                   \
            for (int s = 0; s < 4; ++s)                                         \
                acc[s] = __builtin_amdgcn_mfma_f32_16x16x32_bf16(a[s][kk], BB[kk], acc[s], 0, 0, 0); \
        }                                                                       \
        const float sqjb = (SQJ) + BIAS;                                        \
        _Pragma("unroll")                                                       \
        for (int s = 0; s < 4; ++s) {                                           \
            _Pragma("unroll")                                                   \
            for (int q = 0; q < 4; ++q)                                         \
                T[s][q] = fmaf(-2.f, acc[s][q], ((LABJ) == labi[s][q]) ? sqjb : (SQJ)); \
        }                                                                       \
    } while (0)

    for (int jt = 0; jt < NTILE; jt += 2) {
        MFMA_TILE(bA, tA, sqA, labA);
        if (jt + 2 < NTILE) {   // prefetch tile jt+2 into the A slot
            const __hip_bfloat16* bp = bbase + (size_t)(jt + 2) * 2048;
            #pragma unroll
            for (int kk = 0; kk < 4; ++kk)
                bA[kk] = *reinterpret_cast<const short8*>(bp + kk * 512);
            sqA  = sq[jstart + (jt + 2) * 16 + l15];
            labA = lab[jstart + (jt + 2) * 16 + l15];
        }
        MFMA_TILE(bB, tB, sqB, labB);
        if (jt + 3 < NTILE) {   // prefetch tile jt+3 into the B slot
            const __hip_bfloat16* bp = bbase + (size_t)(jt + 3) * 2048;
            #pragma unroll
            for (int kk = 0; kk < 4; ++kk)
                bB[kk] = *reinterpret_cast<const short8*>(bp + kk * 512);
            sqB  = sq[jstart + (jt + 3) * 16 + l15];
            labB = lab[jstart + (jt + 3) * 16 + l15];
        }
        #pragma unroll
        for (int s = 0; s < 4; ++s)
            #pragma unroll
            for (int q = 0; q < 4; ++q) {
                mx[s][q] = fmaxf(fmaxf(mx[s][q], tA[s][q]), tB[s][q]);
                mn[s][q] = fminf(fminf(mn[s][q], tA[s][q]), tB[s][q]);
            }
    }
    #undef MFMA_TILE

    // reduce over the 16 cols held by the 16 lanes of each g-group
    #pragma unroll
    for (int s = 0; s < 4; ++s)
        #pragma unroll
        for (int q = 0; q < 4; ++q) {
            #pragma unroll
            for (int mk = 1; mk < 16; mk <<= 1) {
                mx[s][q] = fmaxf(mx[s][q], __shfl_xor(mx[s][q], mk, 64));
                mn[s][q] = fminf(mn[s][q], __shfl_xor(mn[s][q], mk, 64));
            }
        }
    if (l15 == 0) {
        #pragma unroll
        for (int s = 0; s < 4; ++s)
            #pragma unroll
            for (int q = 0; q < 4; ++q) {
                const int i = rowbase + s * 16 + g * 4 + q;
                const float sqi = sq[i];
                // keys strictly positive; int order == float order for positives
                const float kpv = sqi + mx[s][q] + KOFF;   // = hp2 + BIAS + KOFF
                const float knv = sqi + mn[s][q] + KOFF;   // = hn2 + KOFF
                atomicMax(&kp[i], __float_as_int(kpv));
                atomicMin(&kn[i], __float_as_int(knv));
            }
    }
}

// ---------------- combine: per-row loss -> scalar ----------------
__global__ __launch_bounds__(256) void combine_kernel(
    const int* __restrict__ kp, const int* __restrict__ kn,
    float* __restrict__ acc_sum, int* __restrict__ done,
    float* __restrict__ out) {
    const int row = blockIdx.x * 256 + threadIdx.x;
    const float hp2 = __int_as_float(kp[row]) - BIAS - KOFF;
    const float hn2 = __int_as_float(kn[row]) - KOFF;
    float v = fmaxf(sqrtf(fmaxf(hp2, 0.f)) - sqrtf(fmaxf(hn2, 0.f)) + 1.0f, 0.f);
    #pragma unroll
    for (int mk = 1; mk < 64; mk <<= 1) v += __shfl_xor(v, mk, 64);
    __shared__ float sv[4];
    const int wv = threadIdx.x >> 6;
    if ((threadIdx.x & 63) == 0) sv[wv] = v;
    __syncthreads();
    if (threadIdx.x == 0) {
        atomicAdd(acc_sum, sv[0] + sv[1] + sv[2] + sv[3]);
        __threadfence();
        const int old = atomicAdd(done, 1);
        if (old == (int)gridDim.x - 1) {
            const float fs = atomicAdd(acc_sum, 0.f);   // coherent read
            out[0] = fs / (float)B_ROWS;
        }
    }
}

// ---------------- launch ----------------
// NOTE: main_kernel launched TWICE this round (outputs are idempotent atomics,
// so results are identical) — timing decomposition probe: main_dur = T(this) - T(single).
extern "C" void kernel_launch(void* const* d_in, const int* in_sizes, int n_in,
                              void* d_out, int out_size, void* d_ws, size_t ws_size,
                              hipStream_t stream) {
    const float* x   = (const float*)d_in[0];
    const int*   lab = (const int*)d_in[1];
    float*       out = (float*)d_out;

    char* ws = (char*)d_ws;
    __hip_bfloat16* xf = (__hip_bfloat16*)ws;
    float* sq      = (float*)(ws + OFF_SQ);
    int*   kp      = (int*)(ws + OFF_KP);
    int*   kn      = (int*)(ws + OFF_KN);
    float* acc_sum = (float*)(ws + OFF_ACC);
    int*   done    = (int*)(ws + OFF_ACC + 4);

    prep_kernel<<<B_ROWS / 4, 256, 0, stream>>>(x, xf, sq, kp, kn, acc_sum, done);
    main_kernel<<<dim3(NRB, NSPLIT), 256, 0, stream>>>(xf, sq, lab, kp, kn);
    main_kernel<<<dim3(NRB, NSPLIT), 256, 0, stream>>>(xf, sq, lab, kp, kn);
    combine_kernel<<<B_ROWS / 256, 256, 0, stream>>>(kp, kn, acc_sum, done, out);
}

// Round 11
// 42.139 us; speedup vs baseline: 1.3546x; 1.3546x over previous
//
#include <hip/hip_runtime.h>
#include <hip/hip_bf16.h>

typedef __attribute__((ext_vector_type(8))) short short8;
typedef __attribute__((ext_vector_type(4))) float floatx4;

#define B_ROWS 8192
#define DIM    128
#define NB     32                       // 256-row blocks
#define NPAIR  (NB * (NB + 1) / 2)      // 528 block-pairs (bi <= bj)
#define WAVES  4
#define RPW    64                       // rows per wave (4 x 16-row MFMA sets)
#define BM     (WAVES * RPW)            // 256 rows per block
#define NTILE  16                       // 256 cols of block-j in 16-col tiles
#define BIAS   4096.0f
#define KOFF   64.0f                    // keeps atomic keys strictly positive

// Fragment-ordered buffer xf: for 16-row tile t, k-slice kk (0..3), lane l (0..63):
//   bf16 index = t*2048 + kk*512 + l*8 + e
// = element (row = t*16 + (l&15), k = kk*32 + (l>>4)*8 + e) — the exact
// mfma_f32_16x16x32_bf16 A/B fragment layout. One tile = 4KB contiguous.
//
// Symmetric key: key(i,j) = d2(i,j) + KOFF + BIAS*same(i,j)  (strictly > 0)
//   hardest_pos2[i] = max_j key - BIAS - KOFF ;  hardest_neg2[i] = min_j key - KOFF
// key is symmetric -> one Gram tile updates row anchors AND col anchors.

// ws layout
#define OFF_SQ  (2u << 20)                 // after 2MB xf
#define OFF_KP  (OFF_SQ + (64u << 10))     // int keys, 32KB
#define OFF_KN  (OFF_KP + (32u << 10))     // int keys, 32KB
#define OFF_ACC (OFF_KN + (32u << 10))     // float sum, int done

// ---------------- prep: f32 -> bf16 fragment-order + norms + key/acc init ----------------
__global__ __launch_bounds__(256) void prep_kernel(const float* __restrict__ x,
                                                   __hip_bfloat16* __restrict__ xf,
                                                   float* __restrict__ sq,
                                                   int* __restrict__ kp,
                                                   int* __restrict__ kn,
                                                   float* __restrict__ acc_sum,
                                                   int* __restrict__ done) {
    const int gid = blockIdx.x * 256 + threadIdx.x;
    if (gid < B_ROWS) { kp[gid] = 0; kn[gid] = 0x7F7F7F7F; }
    if (gid == 0) { acc_sum[0] = 0.f; done[0] = 0; }

    const int row  = blockIdx.x * 4 + (threadIdx.x >> 6);
    const int lane = threadIdx.x & 63;   // holds k = 2*lane, 2*lane+1
    const float2 v = *reinterpret_cast<const float2*>(x + row * DIM + lane * 2);
    __hip_bfloat162 b2;
    b2.x = __float2bfloat16(v.x);
    b2.y = __float2bfloat16(v.y);
    const int kk = lane >> 4;
    const int g  = (lane >> 2) & 3;
    const int e  = (lane & 3) * 2;
    const int idx = (row >> 4) * 2048 + kk * 512 + (g * 16 + (row & 15)) * 8 + e;
    *reinterpret_cast<__hip_bfloat162*>(xf + idx) = b2;
    float s = v.x * v.x + v.y * v.y;
    #pragma unroll
    for (int m = 1; m < 64; m <<= 1) s += __shfl_xor(s, m, 64);
    if (lane == 0) sq[row] = s;
}

// ---------------- main: triangular two-sided Gram + hardest pos/neg ----------------
// grid = NPAIR blocks (bi <= bj), block = 256 (4 waves), 2 waves/SIMD.
// Wave owns 64 rows of block bi; streams block bj's 256 cols (16 tiles) with
// depth-2 register prefetch, barrier-free loop. Row-side extremes in registers;
// col-side extremes via per-tile lane-tree + LDS atomics; one flush at the end.
__global__ __launch_bounds__(256, 2) void main_kernel(
    const __hip_bfloat16* __restrict__ xf,
    const float* __restrict__ sq,
    const int*  __restrict__ lab,
    int* __restrict__ kp,
    int* __restrict__ kn) {
    __shared__ int kpL[256];
    __shared__ int knL[256];

    const int tid  = threadIdx.x;
    const int lane = tid & 63;
    const int wave = tid >> 6;
    const int l15  = lane & 15;
    const int g    = lane >> 4;

    // decode triangular pair (bi <= bj)
    int bi = 0, rem = blockIdx.x;
    while (rem >= NB - bi) { rem -= NB - bi; ++bi; }
    const int bj = bi + rem;

    const int rowbase = bi * BM + wave * RPW;
    const int colbase = bj * BM;

    if (tid < 256) { kpL[tid] = 0; knL[tid] = 0x7F7F7F7F; }

    // A fragments: 4 sets x 16 rows
    short8 a[4][4];
    #pragma unroll
    for (int s = 0; s < 4; ++s) {
        const __hip_bfloat16* ap = xf + ((size_t)(rowbase >> 4) + s) * 2048 + lane * 8;
        #pragma unroll
        for (int kk = 0; kk < 4; ++kk)
            a[s][kk] = *reinterpret_cast<const short8*>(ap + kk * 512);
    }
    int labi[4][4]; float sqi[4][4];
    #pragma unroll
    for (int s = 0; s < 4; ++s)
        #pragma unroll
        for (int q = 0; q < 4; ++q) {
            const int i = rowbase + s * 16 + g * 4 + q;
            labi[s][q] = lab[i];
            sqi[s][q]  = sq[i];
        }

    float mx[4][4], mn[4][4];
    #pragma unroll
    for (int s = 0; s < 4; ++s)
        #pragma unroll
        for (int q = 0; q < 4; ++q) { mx[s][q] = -INFINITY; mn[s][q] = INFINITY; }

    const __hip_bfloat16* bbase = xf + (size_t)(colbase >> 4) * 2048 + lane * 8;

    short8 bA[4], bB[4];
    float sqA, sqB; int labA, labB;
    #pragma unroll
    for (int kk = 0; kk < 4; ++kk) {
        bA[kk] = *reinterpret_cast<const short8*>(bbase + kk * 512);
        bB[kk] = *reinterpret_cast<const short8*>(bbase + 2048 + kk * 512);
    }
    sqA = sq[colbase + l15];        labA = lab[colbase + l15];
    sqB = sq[colbase + 16 + l15];   labB = lab[colbase + 16 + l15];

    __syncthreads();   // kpL/knL initialized

    #define MFMA_TILE(BB, SQJ, LABJ, JT)                                        \
    do {                                                                        \
        floatx4 acc[4];                                                         \
        _Pragma("unroll")                                                       \
        for (int s = 0; s < 4; ++s) acc[s] = (floatx4){0.f, 0.f, 0.f, 0.f};     \
        _Pragma("unroll")                                                       \
        for (int kk = 0; kk < 4; ++kk) {                                        \
            _Pragma("unroll")                                                   \
            for (int s = 0; s < 4; ++s)                                         \
                acc[s] = __builtin_amdgcn_mfma_f32_16x16x32_bf16(a[s][kk], BB[kk], acc[s], 0, 0, 0); \
        }                                                                       \
        const float sjk  = (SQJ) + KOFF;                                        \
        const float sjkb = sjk + BIAS;                                          \
        float cmax = -INFINITY, cmin = INFINITY;                                \
        _Pragma("unroll")                                                       \
        for (int s = 0; s < 4; ++s) {                                           \
            _Pragma("unroll")                                                   \
            for (int q = 0; q < 4; ++q) {                                       \
                const float key = fmaf(-2.f, acc[s][q],                         \
                    (((LABJ) == labi[s][q]) ? sjkb : sjk) + sqi[s][q]);         \
                mx[s][q] = fmaxf(mx[s][q], key);                                \
                mn[s][q] = fminf(mn[s][q], key);                                \
                cmax = fmaxf(cmax, key);                                        \
                cmin = fminf(cmin, key);                                        \
            }                                                                   \
        }                                                                       \
        cmax = fmaxf(cmax, __shfl_xor(cmax, 16, 64));                           \
        cmax = fmaxf(cmax, __shfl_xor(cmax, 32, 64));                           \
        cmin = fminf(cmin, __shfl_xor(cmin, 16, 64));                           \
        cmin = fminf(cmin, __shfl_xor(cmin, 32, 64));                           \
        if (g == 0) {                                                           \
            atomicMax(&kpL[(JT) * 16 + l15], __float_as_int(cmax));             \
            atomicMin(&knL[(JT) * 16 + l15], __float_as_int(cmin));             \
        }                                                                       \
    } while (0)

    for (int jt = 0; jt < NTILE; jt += 2) {
        MFMA_TILE(bA, sqA, labA, jt);
        if (jt + 2 < NTILE) {
            const __hip_bfloat16* bp = bbase + (size_t)(jt + 2) * 2048;
            #pragma unroll
            for (int kk = 0; kk < 4; ++kk)
                bA[kk] = *reinterpret_cast<const short8*>(bp + kk * 512);
            sqA  = sq[colbase + (jt + 2) * 16 + l15];
            labA = lab[colbase + (jt + 2) * 16 + l15];
        }
        MFMA_TILE(bB, sqB, labB, jt + 1);
        if (jt + 3 < NTILE) {
            const __hip_bfloat16* bp = bbase + (size_t)(jt + 3) * 2048;
            #pragma unroll
            for (int kk = 0; kk < 4; ++kk)
                bB[kk] = *reinterpret_cast<const short8*>(bp + kk * 512);
            sqB  = sq[colbase + (jt + 3) * 16 + l15];
            labB = lab[colbase + (jt + 3) * 16 + l15];
        }
    }
    #undef MFMA_TILE

    // row-side: reduce over the 16 cols held by the l15 lanes, then global atomics
    #pragma unroll
    for (int s = 0; s < 4; ++s)
        #pragma unroll
        for (int q = 0; q < 4; ++q) {
            #pragma unroll
            for (int mk = 1; mk < 16; mk <<= 1) {
                mx[s][q] = fmaxf(mx[s][q], __shfl_xor(mx[s][q], mk, 64));
                mn[s][q] = fminf(mn[s][q], __shfl_xor(mn[s][q], mk, 64));
            }
        }
    if (l15 == 0) {
        #pragma unroll
        for (int s = 0; s < 4; ++s)
            #pragma unroll
            for (int q = 0; q < 4; ++q) {
                const int i = rowbase + s * 16 + g * 4 + q;
                atomicMax(&kp[i], __float_as_int(mx[s][q]));
                atomicMin(&kn[i], __float_as_int(mn[s][q]));
            }
    }

    // col-side: flush the block-local col table
    __syncthreads();
    if (tid < 256) {
        atomicMax(&kp[colbase + tid], kpL[tid]);
        atomicMin(&kn[colbase + tid], knL[tid]);
    }
}

// ---------------- combine: per-row loss -> scalar ----------------
__global__ __launch_bounds__(256) void combine_kernel(
    const int* __restrict__ kp, const int* __restrict__ kn,
    float* __restrict__ acc_sum, int* __restrict__ done,
    float* __restrict__ out) {
    const int row = blockIdx.x * 256 + threadIdx.x;
    const float hp2 = __int_as_float(kp[row]) - BIAS - KOFF;
    const float hn2 = __int_as_float(kn[row]) - KOFF;
    float v = fmaxf(sqrtf(fmaxf(hp2, 0.f)) - sqrtf(fmaxf(hn2, 0.f)) + 1.0f, 0.f);
    #pragma unroll
    for (int mk = 1; mk < 64; mk <<= 1) v += __shfl_xor(v, mk, 64);
    __shared__ float sv[4];
    const int wv = threadIdx.x >> 6;
    if ((threadIdx.x & 63) == 0) sv[wv] = v;
    __syncthreads();
    if (threadIdx.x == 0) {
        atomicAdd(acc_sum, sv[0] + sv[1] + sv[2] + sv[3]);
        __threadfence();
        const int old = atomicAdd(done, 1);
        if (old == (int)gridDim.x - 1) {
            const float fs = atomicAdd(acc_sum, 0.f);   // coherent read
            out[0] = fs / (float)B_ROWS;
        }
    }
}

// ---------------- launch ----------------
extern "C" void kernel_launch(void* const* d_in, const int* in_sizes, int n_in,
                              void* d_out, int out_size, void* d_ws, size_t ws_size,
                              hipStream_t stream) {
    const float* x   = (const float*)d_in[0];
    const int*   lab = (const int*)d_in[1];
    float*       out = (float*)d_out;

    char* ws = (char*)d_ws;
    __hip_bfloat16* xf = (__hip_bfloat16*)ws;
    float* sq      = (float*)(ws + OFF_SQ);
    int*   kp      = (int*)(ws + OFF_KP);
    int*   kn      = (int*)(ws + OFF_KN);
    float* acc_sum = (float*)(ws + OFF_ACC);
    int*   done    = (int*)(ws + OFF_ACC + 4);

    prep_kernel<<<B_ROWS / 4, 256, 0, stream>>>(x, xf, sq, kp, kn, acc_sum, done);
    main_kernel<<<NPAIR, 256, 0, stream>>>(xf, sq, lab, kp, kn);
    combine_kernel<<<B_ROWS / 256, 256, 0, stream>>>(kp, kn, acc_sum, done, out);
}